// Round 9
// baseline (283.021 us; speedup 1.0000x reference)
//
#include <hip/hip_runtime.h>
#include <stdint.h>

#define GRID_Z 10
#define GRID_Y 400
#define GRID_X 352
#define NGRID (GRID_Z * GRID_Y * GRID_X)   // 1,408,000
#define NVOX 200000
#define CCH 128
#define MROI 64
#define GXD 64
#define GYD 32
#define GZD 4
#define GCELLS 8192                         // GXD*GYD*GZD
#define NTAPS 147                           // 7*7*3
#define TROWS 32                            // voxel rows per tile
#define NSLC 12                             // slices per ROI -> 768 blocks = 3/CU
#define PITCH 136                           // bf16 units per LDS feat row (128+8)
#define NTT 10                              // tap-tiles of 16 (160 padded taps)
#define BFRAGN (NTT * 4 * 64)               // uint4 entries per plane (2560)
#define VCLR ((NGRID / 4 + 255) / 256)      // v2p-clear blocks (int4): 1375
#define ABLK 16                             // argfin blocks per ROI

typedef short bf16x8 __attribute__((ext_vector_type(8)));
typedef float f32x4 __attribute__((ext_vector_type(4)));

__device__ __forceinline__ unsigned f2bf(float x) {   // RNE fp32->bf16 bits
    unsigned u = __float_as_uint(x);
    return (u + 0x7FFFu + ((u >> 16) & 1u)) >> 16;
}
__device__ __forceinline__ float bf2f(unsigned h) {
    return __uint_as_float(h << 16);
}

// Recompute a grid cell's world xyz exactly like the reference (fp32, no fma
// contraction so floor() boundaries match XLA's mul+add evaluation).
__device__ __forceinline__ void cell_xyz(const float* __restrict__ roi, int g,
                                         float& X, float& Y, float& Z) {
#pragma clang fp contract(off)
    int iz = g & 3;
    int iy = (g >> 2) & 31;
    int ix = g >> 7;
    float bx = roi[3] * 2.0f;   // EXTEND on x,y dims
    float by = roi[4] * 2.0f;
    float bz = roi[5];
    float lx = (ix + 0.5f) / 64.0f * bx - bx / 2.0f;
    float ly = (iy + 0.5f) / 32.0f * by - by / 2.0f;
    float lz = (iz + 0.5f) / 4.0f  * bz - bz / 2.0f;
    float c = cosf(roi[6]);
    float s = sinf(roi[6]);
    X = lx * c + ly * (-s) + roi[0];
    Y = lx * s + ly * c    + roi[1];
    Z = lz + roi[2];
}

// ---------------- phase kernels (stream-ordered) ----------------
// prep (fused): blocks 0..9 split fproto into mfma B-frag planes; block 10
// computes per-ROI trig + zeroes cnt/best/done; blocks 11+ clear v2p.
__global__ void k_prep(const float* __restrict__ fproto, const float* __restrict__ rois,
                       uint4* __restrict__ bH, uint4* __restrict__ bL,
                       float2* __restrict__ rtrig, unsigned long long* __restrict__ best,
                       int* __restrict__ cnt, unsigned* __restrict__ done,
                       int* __restrict__ v2p) {
    if (blockIdx.x < NTT) {
        int tT   = blockIdx.x;                 // 0..9
        int ks   = threadIdx.x >> 6;           // 0..3
        int lane = threadIdx.x & 63;
        int tap  = tT * 16 + (lane & 15);
        int k0   = ks * 32 + (lane >> 4) * 8;
        unsigned hi[8], lo[8];
        #pragma unroll
        for (int j = 0; j < 8; ++j) {
            float x = (tap < NTAPS) ? fproto[tap * CCH + k0 + j] : 0.0f;
            unsigned h = f2bf(x);
            float r = x - bf2f(h);
            hi[j] = h;
            lo[j] = f2bf(r);
        }
        uint4 uh, ul;
        uh.x = hi[0] | (hi[1] << 16); uh.y = hi[2] | (hi[3] << 16);
        uh.z = hi[4] | (hi[5] << 16); uh.w = hi[6] | (hi[7] << 16);
        ul.x = lo[0] | (lo[1] << 16); ul.y = lo[2] | (lo[3] << 16);
        ul.z = lo[4] | (lo[5] << 16); ul.w = lo[6] | (lo[7] << 16);
        int idx = (tT * 4 + ks) * 64 + lane;
        bH[idx] = uh;
        bL[idx] = ul;
    } else if (blockIdx.x == NTT) {
#pragma clang fp contract(off)
        int t = threadIdx.x;
        if (t < MROI) {
            float yaw = rois[t * 7 + 6];
            rtrig[t] = make_float2(cosf(yaw), sinf(yaw));
            cnt[t] = 0;
            best[t] = 0ull;
        }
        if (t == 0) *done = 0u;
    } else {
        int i = (blockIdx.x - NTT - 1) * 256 + threadIdx.x;   // int4 index
        if (i < NGRID / 4) {
            int4* p = (int4*)v2p;
            p[i] = make_int4(-1, -1, -1, -1);
        }
    }
}

__global__ void k_scatter(const int* __restrict__ vcoords, int* __restrict__ v2p) {
    int i = blockIdx.x * 256 + threadIdx.x;
    if (i >= NVOX) return;
    int z = vcoords[i * 4 + 1];
    int y = vcoords[i * 4 + 2];
    int x = vcoords[i * 4 + 3];
    atomicMax(&v2p[(z * GRID_Y + y) * GRID_X + x], i);
}

// build: one thread per (m, ix, iy); 4 iz cells per thread. Trig precomputed.
// fp expressions bit-identical to cell_xyz/cell_to_pidx (X,Y independent of iz).
__global__ void k_build(const float* __restrict__ rois, const float2* __restrict__ rtrig,
                        const int* __restrict__ v2p, unsigned* __restrict__ list,
                        int* __restrict__ cnt) {
#pragma clang fp contract(off)
    int m   = blockIdx.y;
    int idx = blockIdx.x * 256 + threadIdx.x;   // 0..2047
    int ix  = idx >> 5;
    int iy  = idx & 31;
    int lane = threadIdx.x & 63;

    const float* roi = rois + m * 7;
    float c = rtrig[m].x, s = rtrig[m].y;
    float bx = roi[3] * 2.0f;
    float by = roi[4] * 2.0f;
    float bz = roi[5];
    float lx = (ix + 0.5f) / 64.0f * bx - bx / 2.0f;
    float ly = (iy + 0.5f) / 32.0f * by - by / 2.0f;
    float X = lx * c + ly * (-s) + roi[0];
    float Y = lx * s + ly * c    + roi[1];
    float fx = floorf((X - 0.0f)     / 0.05f);
    float fy = floorf((Y - (-40.0f)) / 0.05f);
    int cx = (int)floorf(fx / 4.0f);
    int cy = (int)floorf(fy / 4.0f);
    bool okxy = (cy >= 0 && cy < GRID_Y && cx >= 0 && cx < GRID_X);
    int gbase = (ix << 7) | (iy << 2);

    #pragma unroll
    for (int iz = 0; iz < 4; ++iz) {
        float lz = (iz + 0.5f) / 4.0f * bz - bz / 2.0f;
        float Z  = lz + roi[2];
        float fz = floorf((Z - (-3.0f)) / 0.1f);
        int cz = (int)floorf(fz / 4.0f);
        int p = -1;
        if (okxy && cz >= 0 && cz < GRID_Z)
            p = v2p[(cz * GRID_Y + cy) * GRID_X + cx];
        bool v = p >= 0;
        unsigned long long bal = __ballot(v);
        int nset = __popcll(bal);
        int base = 0;
        if (lane == 0 && nset) base = atomicAdd(&cnt[m], nset);
        base = __shfl(base, 0, 64);
        if (v) {
            int pos = __popcll(bal & ((1ull << lane) - 1ull));
            list[m * GCELLS + base + pos] = ((unsigned)p << 13) | (unsigned)(gbase | iz);
        }
    }
}

// dots: split-bf16 MFMA (R8-proven, unchanged). 4 waves = 2 row-tiles x 2 tap-halves.
__global__ __launch_bounds__(256) void k_dots(
        const float* __restrict__ vfeat, const uint4* __restrict__ bH,
        const uint4* __restrict__ bL, const unsigned* __restrict__ list,
        const int* __restrict__ cnt, float* __restrict__ partial) {
    __shared__ float sscore[GCELLS];                       // 32 KB
    __shared__ __align__(16) unsigned short sAh[TROWS * PITCH];  // 8.7 KB
    __shared__ __align__(16) unsigned short sAl[TROWS * PITCH];  // 8.7 KB
    __shared__ unsigned sg[TROWS];

    const int m    = blockIdx.y;
    const int tid  = threadIdx.x;
    const int w    = tid >> 6;
    const int lane = tid & 63;
    const int rt   = w >> 1;               // row-tile: rows rt*16..+15
    const int th   = w & 1;                // tap-half: taps th*80..+79
    const int col  = lane & 15;
    const int kg   = lane >> 4;            // k-group 0..3
    const int n    = cnt[m];
    const unsigned* lst = list + m * GCELLS;

    int tkx[5], tky[5], tkz[5], tok[5];
    #pragma unroll
    for (int tt = 0; tt < 5; ++tt) {
        int t = th * 80 + tt * 16 + col;
        tok[tt] = t < NTAPS;
        int tc = tok[tt] ? t : 0;
        int kx  = tc / 21;
        int rem = tc - kx * 21;
        tkx[tt] = kx; tky[tt] = rem / 3; tkz[tt] = rem - tky[tt] * 3;
    }
    {   // zero the private score tile
        float4* s4 = (float4*)sscore;
        #pragma unroll
        for (int i = 0; i < GCELLS / 4 / 256; ++i)
            s4[tid + 256 * i] = make_float4(0.f, 0.f, 0.f, 0.f);
    }
    for (int vt0 = blockIdx.x * TROWS; vt0 < n; vt0 += TROWS * NSLC) {
        __syncthreads();                   // score-zero / prior deposits done
        {   // stage 32 rows: 8 threads/row, 16 ch each; split fp32 -> (hi,lo) bf16
            int r = tid >> 3, q = tid & 7, v = vt0 + r;
            unsigned e = 0xFFFFFFFFu;
            if (v < n) e = lst[v];
            if (q == 0) sg[r] = e;
            if (e != 0xFFFFFFFFu) {
                int p = (int)(e >> 13);
                const float4* src = (const float4*)(vfeat + (size_t)p * CCH) + q * 4;
                unsigned hb[16], lb[16];
                #pragma unroll
                for (int j = 0; j < 4; ++j) {
                    float4 s = src[j];
                    float xs[4] = {s.x, s.y, s.z, s.w};
                    #pragma unroll
                    for (int c = 0; c < 4; ++c) {
                        unsigned h = f2bf(xs[c]);
                        hb[j * 4 + c] = h;
                        lb[j * 4 + c] = f2bf(xs[c] - bf2f(h));
                    }
                }
                uint4 h0, h1, l0, l1;
                h0.x = hb[0]  | (hb[1]  << 16); h0.y = hb[2]  | (hb[3]  << 16);
                h0.z = hb[4]  | (hb[5]  << 16); h0.w = hb[6]  | (hb[7]  << 16);
                h1.x = hb[8]  | (hb[9]  << 16); h1.y = hb[10] | (hb[11] << 16);
                h1.z = hb[12] | (hb[13] << 16); h1.w = hb[14] | (hb[15] << 16);
                l0.x = lb[0]  | (lb[1]  << 16); l0.y = lb[2]  | (lb[3]  << 16);
                l0.z = lb[4]  | (lb[5]  << 16); l0.w = lb[6]  | (lb[7]  << 16);
                l1.x = lb[8]  | (lb[9]  << 16); l1.y = lb[10] | (lb[11] << 16);
                l1.z = lb[12] | (lb[13] << 16); l1.w = lb[14] | (lb[15] << 16);
                uint4* dh = (uint4*)((char*)sAh + r * (PITCH * 2) + q * 32);
                uint4* dl = (uint4*)((char*)sAl + r * (PITCH * 2) + q * 32);
                dh[0] = h0; dh[1] = h1;
                dl[0] = l0; dl[1] = l1;
            }
        }
        __syncthreads();
        // A fragments: row = rt*16 + col, k = ks*32 + kg*8 + j
        bf16x8 ah[4], al[4];
        const char* abh = (const char*)sAh + (rt * 16 + col) * (PITCH * 2);
        const char* abl = (const char*)sAl + (rt * 16 + col) * (PITCH * 2);
        #pragma unroll
        for (int ks = 0; ks < 4; ++ks) {
            ah[ks] = *(const bf16x8*)(abh + ks * 64 + kg * 16);
            al[ks] = *(const bf16x8*)(abl + ks * 64 + kg * 16);
        }
        f32x4 acc[5];
        #pragma unroll
        for (int tt = 0; tt < 5; ++tt) acc[tt] = (f32x4){0.f, 0.f, 0.f, 0.f};
        #pragma unroll
        for (int tt = 0; tt < 5; ++tt) {
            const int bi = ((th * 5 + tt) * 4) * 64 + lane;
            #pragma unroll
            for (int ks = 0; ks < 4; ++ks) {
                uint4 uh = bH[bi + ks * 64];
                uint4 ul = bL[bi + ks * 64];
                bf16x8 bh = *(bf16x8*)&uh;
                bf16x8 bl = *(bf16x8*)&ul;
                acc[tt] = __builtin_amdgcn_mfma_f32_16x16x32_bf16(ah[ks], bh, acc[tt], 0, 0, 0);
                acc[tt] = __builtin_amdgcn_mfma_f32_16x16x32_bf16(ah[ks], bl, acc[tt], 0, 0, 0);
                acc[tt] = __builtin_amdgcn_mfma_f32_16x16x32_bf16(al[ks], bh, acc[tt], 0, 0, 0);
            }
        }
        // deposit: D[row][tap] with row = rt*16 + kg*4 + rg, tap col fixed per lane
        #pragma unroll
        for (int tt = 0; tt < 5; ++tt) {
            if (!tok[tt]) continue;
            #pragma unroll
            for (int rg = 0; rg < 4; ++rg) {
                unsigned e = sg[rt * 16 + kg * 4 + rg];
                if (e == 0xFFFFFFFFu) continue;
                int g  = (int)(e & 8191u);
                int cx = (g >> 7)        - (tkx[tt] - 3);
                int cy = ((g >> 2) & 31) - (tky[tt] - 3);
                int cz = (g & 3)         - (tkz[tt] - 1);
                if ((unsigned)cx < (unsigned)GXD && (unsigned)cy < (unsigned)GYD &&
                    (unsigned)cz < (unsigned)GZD)
                    atomicAdd(&sscore[(cx << 7) | (cy << 2) | cz], acc[tt][rg]);
            }
        }
    }
    __syncthreads();                       // all waves' deposits done
    {   // coalesced partial writeback (covers every cell)
        float* dst = partial + ((size_t)m * NSLC + blockIdx.x) * GCELLS;
        const float4* s4 = (const float4*)sscore;
        float4* d4 = (float4*)dst;
        #pragma unroll
        for (int i = 0; i < GCELLS / 4 / 256; ++i)
            d4[tid + 256 * i] = s4[tid + 256 * i];
    }
}

// argfin: 16 blocks/ROI sum the 12 partials over a 512-cell chunk, block-argmax,
// u64 atomicMax into best[m]; globally-last block writes all 64 outputs.
__global__ __launch_bounds__(256) void k_argfin(
        const float* __restrict__ partial, const float* __restrict__ rois,
        const float* __restrict__ pbox, unsigned long long* __restrict__ best,
        unsigned* __restrict__ done, float* __restrict__ out) {
    __shared__ unsigned long long red[256];
    __shared__ unsigned lastflag;
    const int tid = threadIdx.x;
    const int m = blockIdx.y;
    const float* base = partial + (size_t)m * NSLC * GCELLS;
    const int c0 = blockIdx.x * (GCELLS / ABLK);
    unsigned long long bk = 0ull;
    #pragma unroll
    for (int i = 0; i < GCELLS / ABLK / 256; ++i) {
        int c = c0 + tid + 256 * i;
        float v = 0.0f;
        #pragma unroll
        for (int s = 0; s < NSLC; ++s) v += base[s * GCELLS + c];
        unsigned ub  = __float_as_uint(v);
        unsigned key = (ub & 0x80000000u) ? ~ub : (ub | 0x80000000u);  // order-preserving
        unsigned long long pk =
            ((unsigned long long)key << 32) | (unsigned)(GCELLS - 1 - c);  // ties -> smallest g
        bk = bk > pk ? bk : pk;
    }
    red[tid] = bk;
    __syncthreads();
    for (int st = 128; st > 0; st >>= 1) {
        if (tid < st) {
            unsigned long long o = red[tid + st];
            if (o > red[tid]) red[tid] = o;
        }
        __syncthreads();
    }
    if (tid == 0) {
        atomicMax(&best[m], red[0]);
        __threadfence();                       // publish before signalling done
        unsigned d = atomicAdd(done, 1u);
        lastflag = (d == ABLK * MROI - 1u);
    }
    __syncthreads();
    if (lastflag && tid < MROI) {
        // atomic read -> sees all prior atomicMax on the same address
        unsigned long long bv = atomicMax(&best[tid], 0ull);
        int g = (GCELLS - 1) - (int)(unsigned)(bv & 0xFFFFFFFFu);
        float X, Y, Z;
        cell_xyz(rois + tid * 7, g, X, Y, Z);
        out[tid * 7 + 0] = X;
        out[tid * 7 + 1] = Y;
        out[tid * 7 + 2] = Z;
        out[tid * 7 + 3] = pbox[3];
        out[tid * 7 + 4] = pbox[4];
        out[tid * 7 + 5] = pbox[5];
        out[tid * 7 + 6] = pbox[6];
    }
}

extern "C" void kernel_launch(void* const* d_in, const int* in_sizes, int n_in,
                              void* d_out, int out_size, void* d_ws, size_t ws_size,
                              hipStream_t stream) {
    const float* rois    = (const float*)d_in[0];
    const float* pbox    = (const float*)d_in[1];
    const float* vfeat   = (const float*)d_in[2];
    const float* fproto  = (const float*)d_in[3];
    const int*   vcoords = (const int*)d_in[4];
    float* out = (float*)d_out;

    // ws layout: v2p | list | partial(12) | bH | bL | rtrig | best | cnt | done
    int*      v2p     = (int*)d_ws;                              // NGRID ints
    unsigned* list    = (unsigned*)(v2p + NGRID);                // MROI*GCELLS
    float*    partial = (float*)(list + (size_t)MROI * GCELLS);  // 12*MROI*GCELLS floats
    uint4*    bH      = (uint4*)(partial + (size_t)NSLC * MROI * GCELLS);
    uint4*    bL      = bH + BFRAGN;
    float2*   rtrig   = (float2*)(bL + BFRAGN);                  // 64 float2
    unsigned long long* best = (unsigned long long*)(rtrig + MROI);
    int*      cnt     = (int*)(best + MROI);                     // 64 ints
    unsigned* done    = (unsigned*)(cnt + MROI);                 // 1 uint

    k_prep   <<<NTT + 1 + VCLR, 256, 0, stream>>>(fproto, rois, bH, bL, rtrig,
                                                  best, cnt, done, v2p);
    k_scatter<<<(NVOX + 255) / 256, 256, 0, stream>>>(vcoords, v2p);
    k_build  <<<dim3(8, MROI), 256, 0, stream>>>(rois, rtrig, v2p, list, cnt);
    k_dots   <<<dim3(NSLC, MROI), 256, 0, stream>>>(vfeat, bH, bL, list, cnt, partial);
    k_argfin <<<dim3(ABLK, MROI), 256, 0, stream>>>(partial, rois, pbox, best, done, out);
}